// Round 14
// baseline (145.054 us; speedup 1.0000x reference)
//
#include <hip/hip_runtime.h>

// Problem constants
#define BB 8
#define QQ 128
#define KK 1024
#define DD 256
#define HH 256

// scoreav split-K: 32 chunks of 32 k
#define KSP 32
#define KCH 32

#define TWO_LOG2E     2.8853900817779268f
#define NEG_TWO_LOG2E -2.8853900817779268f

// ---------------------------------------------------------------------------
// K1: fused Q+K projection with exp2 epilogue — R8/R12 version (known good).
// Both A and W staged through LDS; 64x64 tile; 576 blocks, mask-skipped.
// (R13's D-split x2 was net-neutral: proj gain cancelled by scoreav's doubled
// staging loads. Reverted to the simpler form.)
// ---------------------------------------------------------------------------
__global__ __launch_bounds__(256) void proj_kernel(const float* __restrict__ queries,
                                                   const float* __restrict__ keys,
                                                   const float* __restrict__ Wq,
                                                   const float* __restrict__ Wk,
                                                   const int* __restrict__ vlen,
                                                   float* __restrict__ eproj) {
    const int r0 = blockIdx.x * 64;
    const bool isQ = (r0 < BB * QQ);
    if (!isQ) {
        const int kb = (r0 - BB * QQ) >> 6;
        const int b  = kb >> 4;
        const int k0 = (kb & 15) << 6;
        if (k0 >= vlen[b]) return;               // fully masked (vl==0 too)
    }

    __shared__ float As[64][68];  // pad 68: <=2-way banks (free)
    __shared__ float Ws[64][68];
    const int t  = threadIdx.x;
    const int tr = t & 15;
    const int th = t >> 4;
    const int h0 = blockIdx.y * 64;
    const float* A = isQ ? (queries + (size_t)r0 * DD)
                         : (keys + (size_t)(r0 - BB * QQ) * DD);
    const float* W = isQ ? Wq : Wk;

    float acc[4][4] = {};

    for (int dc = 0; dc < DD; dc += 64) {
#pragma unroll
        for (int i = 0; i < 4; ++i) {
            int fi  = t + 256 * i;
            int row = fi >> 4;
            int c4  = (fi & 15) << 2;
            *(float4*)&As[row][c4] = *(const float4*)&A[(size_t)row * DD + dc + c4];
            *(float4*)&Ws[row][c4] = *(const float4*)&W[(size_t)(h0 + row) * DD + dc + c4];
        }
        __syncthreads();
#pragma unroll 4
        for (int dd = 0; dd < 64; dd += 4) {
            float4 a4[4], w4[4];
#pragma unroll
            for (int i = 0; i < 4; ++i) a4[i] = *(float4*)&As[tr + 16 * i][dd];
#pragma unroll
            for (int i = 0; i < 4; ++i) w4[i] = *(float4*)&Ws[th + 16 * i][dd];
#pragma unroll
            for (int ri = 0; ri < 4; ++ri)
#pragma unroll
                for (int hi = 0; hi < 4; ++hi) {
                    acc[ri][hi] += a4[ri].x * w4[hi].x + a4[ri].y * w4[hi].y +
                                   a4[ri].z * w4[hi].z + a4[ri].w * w4[hi].w;
                }
        }
        __syncthreads();
    }
#pragma unroll
    for (int ri = 0; ri < 4; ++ri)
#pragma unroll
        for (int hi = 0; hi < 4; ++hi) {
            eproj[(size_t)(r0 + tr + 16 * ri) * HH + h0 + th + 16 * hi] =
                __builtin_amdgcn_exp2f(TWO_LOG2E * acc[ri][hi]);
        }
}

// ---------------------------------------------------------------------------
// K2: FUSED score + A*V v4 — occupancy diet. v3 sat at 128 VGPR + 71 KB LDS
// = 2 blocks/CU = 4 waves/SIMD; three rewrites all plateaued at ~35 us
// (trans floor ~10) -> waves/SIMD is the untested binder.
// v4: h staged in TWO halves, st[2][32][132] = 33.8 KB (132 = 4 mod 32:
// fragment reads hit 8 addr x 4 banks = 32 banks, conflict-free; red alias
// = 33792 B exactly fits st) + pT = 38.4 KB total -> 4 blocks/CU by LDS.
// __launch_bounds__(512,6) caps ~85 VGPR -> 3 blocks/CU = 6 waves/SIMD.
// Wave w owns h-window [16w,16w+16) per half; thread = 4q x 4k.
// ---------------------------------------------------------------------------
__global__ __launch_bounds__(512, 6) void scoreav_kernel(const float* __restrict__ eproj,
                                                         const float* __restrict__ wv,
                                                         const int* __restrict__ vlen,
                                                         const float* __restrict__ V,
                                                         float* __restrict__ partial,
                                                         float* __restrict__ psum) {
    // ---- work-item compaction (uniform scalar scan) ----
    int id = blockIdx.x;
    int b = 0;
    bool found = false;
#pragma unroll
    for (int bb = 0; bb < BB; ++bb) {
        if (!found) {
            int v = vlen[bb];
            int cnt = ((v == 0) ? KSP : ((v + KCH - 1) / KCH)) * 4;
            if (id < cnt) { b = bb; found = true; }
            else id -= cnt;
        }
    }
    if (!found) return;
    const int ksb = id >> 2;
    const int q0  = (id & 3) * 32;
    const int k0  = ksb * KCH;
    const int vl  = vlen[b];

    __shared__ float st[2][32][132];   // [0]=q rows, [1]=k rows; one h-half. 33.8 KB
    __shared__ float pT[KCH][36];      // [k][q]
    float* red = &st[0][0][0];         // alias: red[w*1056 + q*33 + k], 8448 floats

    const int t = threadIdx.x;
    const int w = t >> 6;              // wave 0..7
    const int l = t & 63;
    const int ql = l & 7;              // q rows {ql + 8i}
    const int kl = l >> 3;             // k rows {kl + 8j}

    float acc[4][4] = {};

    if (vl > 0) {
#pragma unroll
        for (int hp = 0; hp < 2; ++hp) {           // two h-halves of 128
            const int hb = hp * 128;
            // stage q (32 rows) + k (32 rows) x 128 h: 2048 f4, 4 per thread
#pragma unroll
            for (int i = 0; i < 4; ++i) {
                int fi  = t + 512 * i;             // 0..2047
                int row = fi >> 5;                 // 0..63
                int c4  = (fi & 31) << 2;          // 0..124
                size_t gr = (row < 32) ? (size_t)(b * QQ + q0 + row)
                                       : (size_t)(BB * QQ + b * KK + k0 + row - 32);
                *(float4*)&st[row >> 5][row & 31][c4] =
                    *(const float4*)&eproj[gr * HH + hb + c4];
            }
            __syncthreads();

            const int hw = 16 * w;                 // wave's h window in this half
#pragma unroll 2
            for (int hh = 0; hh < 16; hh += 4) {
                const float4 w4 = *(const float4*)&wv[hb + hw + hh];  // wave-uniform
                const float* wa = (const float*)&w4;
                float4 q4[4], k4[4];
#pragma unroll
                for (int i = 0; i < 4; ++i) q4[i] = *(float4*)&st[0][ql + 8 * i][hw + hh];
#pragma unroll
                for (int j = 0; j < 4; ++j) k4[j] = *(float4*)&st[1][kl + 8 * j][hw + hh];
#pragma unroll
                for (int i = 0; i < 4; ++i) {
                    const float* qa = (const float*)&q4[i];
#pragma unroll
                    for (int j = 0; j < 4; ++j) {
                        const float* ka = (const float*)&k4[j];
#pragma unroll
                        for (int c = 0; c < 4; ++c) {
                            float d = __builtin_fmaf(qa[c], ka[c], 1.0f);
                            acc[i][j] += wa[c] * __builtin_amdgcn_rcpf(d);
                        }
                    }
                }
            }
            __syncthreads();   // all reads done before restage / red alias
        }

        // wave-partial accs -> red (aliased over dead staging LDS)
#pragma unroll
        for (int i = 0; i < 4; ++i)
#pragma unroll
            for (int j = 0; j < 4; ++j)
                red[w * 1056 + (ql + 8 * i) * 33 + (kl + 8 * j)] = acc[i][j];
    }
    __syncthreads();

    // ---- combine across waves, masked exp2, pT + psum ----
    float pvv[2];
#pragma unroll
    for (int u = 0; u < 2; ++u) {
        int n = t + 512 * u;               // 0..1023
        int q = n >> 5, k = n & 31;
        float s = 0.f;
        if (vl > 0) {
#pragma unroll
            for (int ww = 0; ww < 8; ++ww) s += red[ww * 1056 + q * 33 + k];
        }
        int kg = k0 + k;
        float pv;
        if (vl == 0) pv = 1.0f;            // uniform row (ref behavior)
        else pv = (kg < vl) ? __builtin_amdgcn_exp2f(NEG_TWO_LOG2E * s) : 0.0f;
        pT[k][q] = pv;
        pvv[u] = pv;
    }
    // psum: lanes 0-31 / 32-63 of each wave share a q; reduce within halves
    float s0 = pvv[0], s1 = pvv[1];
#pragma unroll
    for (int off = 1; off < 32; off <<= 1) {
        s0 += __shfl_xor(s0, off);
        s1 += __shfl_xor(s1, off);
    }
    if ((l & 31) == 0) {
        int qa = 2 * w + (l >> 5);         // q for u=0; u=1 is qa+16
        psum[((size_t)ksb * BB + b) * QQ + q0 + qa]      = s0;
        psum[((size_t)ksb * BB + b) * QQ + q0 + qa + 16] = s1;
    }
    __syncthreads();

    // ---- av phase: thread = (4d x 4q), 8 q-groups over 8 waves ----
    const float* VB = V + ((size_t)b * KK + k0) * DD;
    const int d4 = (t & 63) << 2;
    const int qg = w << 2;                 // 0,4,...,28
    float4 a4[4] = {};
#pragma unroll 4
    for (int k = 0; k < KCH; ++k) {
        float4 v4 = *(const float4*)&VB[(size_t)k * DD + d4];   // coalesced
        float4 p4 = *(float4*)&pT[k][qg];                       // broadcast
        a4[0].x += p4.x * v4.x; a4[0].y += p4.x * v4.y; a4[0].z += p4.x * v4.z; a4[0].w += p4.x * v4.w;
        a4[1].x += p4.y * v4.x; a4[1].y += p4.y * v4.y; a4[1].z += p4.y * v4.z; a4[1].w += p4.y * v4.w;
        a4[2].x += p4.z * v4.x; a4[2].y += p4.z * v4.y; a4[2].z += p4.z * v4.z; a4[2].w += p4.z * v4.w;
        a4[3].x += p4.w * v4.x; a4[3].y += p4.w * v4.y; a4[3].z += p4.w * v4.z; a4[3].w += p4.w * v4.w;
    }
#pragma unroll
    for (int qi = 0; qi < 4; ++qi) {
        int q = q0 + qg + qi;
        *(float4*)&partial[(((size_t)ksb * BB + b) * QQ + q) * DD + d4] = a4[qi];
    }
}

// ---------------------------------------------------------------------------
// K3: mask-aware reduce over the nch(b) live chunks + softmax normalization.
// ---------------------------------------------------------------------------
__global__ __launch_bounds__(256) void av_reduce(const float* __restrict__ partial,
                                                 const float* __restrict__ psum,
                                                 const int* __restrict__ vlen,
                                                 float* __restrict__ out) {
    const int i  = blockIdx.x * 256 + threadIdx.x;   // float4 index, 65536 total
    const int bq = i >> 6;                           // b*QQ + q
    const int b  = bq >> 7;
    const int vl = vlen[b];
    const int nch = (vl == 0) ? KSP : ((vl + KCH - 1) / KCH);

    float S = 0.f;
    for (int ks = 0; ks < nch; ++ks) S += psum[(size_t)ks * (BB * QQ) + bq];

    const float4* p4 = (const float4*)partial;
    const int stride4 = BB * QQ * DD / 4;            // 65536
    float4 s = {0.f, 0.f, 0.f, 0.f};
    for (int ks = 0; ks < nch; ++ks) {
        float4 x = p4[(size_t)ks * stride4 + i];
        s.x += x.x; s.y += x.y; s.z += x.z; s.w += x.w;
    }
    const float inv = 1.0f / S;   // S>0 always: p>=8e-12 unmasked, vl==0 -> p=1
    s.x *= inv; s.y *= inv; s.z *= inv; s.w *= inv;
    ((float4*)out)[i] = s;
}

// ---------------------------------------------------------------------------
extern "C" void kernel_launch(void* const* d_in, const int* in_sizes, int n_in,
                              void* d_out, int out_size, void* d_ws, size_t ws_size,
                              hipStream_t stream) {
    const float* queries = (const float*)d_in[0];   // [B,Q,D]
    const float* keys    = (const float*)d_in[1];   // [B,K,D]
    const float* values  = (const float*)d_in[2];   // [B,K,D]
    const float* W_q     = (const float*)d_in[3];   // [H,D]
    const float* W_k     = (const float*)d_in[4];   // [H,D]
    const float* w_v     = (const float*)d_in[5];   // [H]
    const int*   vlen    = (const int*)d_in[6];     // [B]
    float* out = (float*)d_out;

    float* ws      = (float*)d_ws;
    float* eproj   = ws;                                        // 2359296 floats
    float* psum    = eproj + (size_t)(BB * QQ + BB * KK) * HH;  // KSP*B*Q = 32768
    float* partial = psum + (size_t)KSP * BB * QQ;              // 33.5 MB
    // no aliasing: scoreav reads eproj while writing partial. ~45 MB of ws.

    // Fused Q+K projection with exp2 epilogue (R8/R12 version), mask-skipped
    proj_kernel<<<dim3((BB * QQ + BB * KK) / 64, HH / 64, 1), 256, 0, stream>>>(
        queries, keys, W_q, W_k, vlen, eproj);

    // Fused score + A*V v4 (6 waves/SIMD target), full 1024-item launch
    scoreav_kernel<<<dim3(KSP * 4 * BB, 1, 1), 512, 0, stream>>>(
        eproj, w_v, vlen, values, partial, psum);

    // Mask-aware reduce + softmax normalization
    av_reduce<<<dim3(BB * QQ * DD / 4 / 256, 1, 1), 256, 0, stream>>>(
        partial, psum, vlen, out);
}

// Round 15
// 142.225 us; speedup vs baseline: 1.0199x; 1.0199x over previous
//
#include <hip/hip_runtime.h>

// Problem constants
#define BB 8
#define QQ 128
#define KK 1024
#define DD 256
#define HH 256

// scoreav split-K: 32 chunks of 32 k
#define KSP 32
#define KCH 32

// proj D-split
#define RTOT (BB * QQ + BB * KK)          // 9216 rows
#define PSTRIDE ((size_t)RTOT * HH)       // floats per D-half buffer

#define TWO_LOG2E     2.8853900817779268f
#define NEG_TWO_LOG2E -2.8853900817779268f

// ---------------------------------------------------------------------------
// K1: Q+K projection, D-SPLIT x2 (R13 best-measured config, 142.72 us).
// Block (r-tile 64, h-tile 64, z in {0,1}); z accumulates d in [128z,128z+128)
// and writes pp[z] = 2log2e * acc_half; scoreav staging computes exp2(pp0+pp1).
// MASK SKIP: key blocks fully >= vl[b] -> early out.
// ---------------------------------------------------------------------------
__global__ __launch_bounds__(256) void proj_kernel(const float* __restrict__ queries,
                                                   const float* __restrict__ keys,
                                                   const float* __restrict__ Wq,
                                                   const float* __restrict__ Wk,
                                                   const int* __restrict__ vlen,
                                                   float* __restrict__ pp) {
    const int r0 = blockIdx.x * 64;
    const bool isQ = (r0 < BB * QQ);
    if (!isQ) {
        const int kb = (r0 - BB * QQ) >> 6;
        const int b  = kb >> 4;
        const int k0 = (kb & 15) << 6;
        if (k0 >= vlen[b]) return;               // fully masked (vl==0 too)
    }

    __shared__ float As[64][68];  // pad 68: <=2-way banks (free)
    __shared__ float Ws[64][68];
    const int t  = threadIdx.x;
    const int tr = t & 15;
    const int th = t >> 4;
    const int h0 = blockIdx.y * 64;
    const int dc0 = blockIdx.z * 128;            // D-half base
    const float* A = isQ ? (queries + (size_t)r0 * DD)
                         : (keys + (size_t)(r0 - BB * QQ) * DD);
    const float* W = isQ ? Wq : Wk;

    float acc[4][4] = {};

    for (int dc = dc0; dc < dc0 + 128; dc += 64) {
#pragma unroll
        for (int i = 0; i < 4; ++i) {
            int fi  = t + 256 * i;
            int row = fi >> 4;
            int c4  = (fi & 15) << 2;
            *(float4*)&As[row][c4] = *(const float4*)&A[(size_t)row * DD + dc + c4];
            *(float4*)&Ws[row][c4] = *(const float4*)&W[(size_t)(h0 + row) * DD + dc + c4];
        }
        __syncthreads();
#pragma unroll 4
        for (int dd = 0; dd < 64; dd += 4) {
            float4 a4[4], w4[4];
#pragma unroll
            for (int i = 0; i < 4; ++i) a4[i] = *(float4*)&As[tr + 16 * i][dd];
#pragma unroll
            for (int i = 0; i < 4; ++i) w4[i] = *(float4*)&Ws[th + 16 * i][dd];
#pragma unroll
            for (int ri = 0; ri < 4; ++ri)
#pragma unroll
                for (int hi = 0; hi < 4; ++hi) {
                    acc[ri][hi] += a4[ri].x * w4[hi].x + a4[ri].y * w4[hi].y +
                                   a4[ri].z * w4[hi].z + a4[ri].w * w4[hi].w;
                }
        }
        __syncthreads();
    }

    float* outp = pp + (size_t)blockIdx.z * PSTRIDE;
#pragma unroll
    for (int ri = 0; ri < 4; ++ri)
#pragma unroll
        for (int hi = 0; hi < 4; ++hi) {
            outp[(size_t)(r0 + tr + 16 * ri) * HH + h0 + th + 16 * hi] =
                TWO_LOG2E * acc[ri][hi];
        }
}

// ---------------------------------------------------------------------------
// K2: FUSED score + A*V v3 (R13 best-measured). h-sliced 8 waves, one-shot
// staging combining the two proj D-halves: st = exp2(pp0 + pp1). Zero
// barriers in the h-loop, conflict-free fragment reads (stride 260 = 4 mod
// 32), VGPR-bound 4 waves/SIMD. (v4's 6-waves/SIMD diet was flat-to-negative
// — occupancy is NOT scoreav's binder; reverted.)
// ---------------------------------------------------------------------------
__global__ __launch_bounds__(512, 4) void scoreav_kernel(const float* __restrict__ pp,
                                                         const float* __restrict__ wv,
                                                         const int* __restrict__ vlen,
                                                         const float* __restrict__ V,
                                                         float* __restrict__ partial,
                                                         float* __restrict__ psum) {
    // ---- work-item compaction (uniform scalar scan) ----
    int id = blockIdx.x;
    int b = 0;
    bool found = false;
#pragma unroll
    for (int bb = 0; bb < BB; ++bb) {
        if (!found) {
            int v = vlen[bb];
            int cnt = ((v == 0) ? KSP : ((v + KCH - 1) / KCH)) * 4;
            if (id < cnt) { b = bb; found = true; }
            else id -= cnt;
        }
    }
    if (!found) return;
    const int ksb = id >> 2;
    const int q0  = (id & 3) * 32;
    const int k0  = ksb * KCH;
    const int vl  = vlen[b];

    __shared__ float st[2][32][260];   // [0]=q rows, [1]=k rows; all 256 h. 66.6 KB
    __shared__ float pT[KCH][36];      // [k][q]
    float* red = &st[0][0][0];         // alias: red[w*1056 + q*33 + k] (33.8 KB)

    const int t = threadIdx.x;
    const int w = t >> 6;              // wave 0..7
    const int l = t & 63;
    const int ql = l & 7;              // q rows {ql + 8i}
    const int kl = l >> 3;             // k rows {kl + 8j}

    float acc[4][4] = {};

    if (vl > 0) {
        // stage q (32 rows) + k (32 rows) x 256 h: 4096 f4, 8 per thread;
        // combine D-halves + exp2 inline. Coalesced 1 KB/wave row reads.
#pragma unroll
        for (int i = 0; i < 8; ++i) {
            int fi  = t + 512 * i;             // 0..4095
            int row = fi >> 6;                 // 0..63
            int c4  = (fi & 63) << 2;          // 0..252
            size_t gr = (row < 32) ? (size_t)(b * QQ + q0 + row)
                                   : (size_t)(BB * QQ + b * KK + k0 + row - 32);
            const float* base = pp + gr * HH + c4;
            float4 v0 = *(const float4*)base;
            float4 v1 = *(const float4*)(base + PSTRIDE);
            float4 s;
            s.x = __builtin_amdgcn_exp2f(v0.x + v1.x);
            s.y = __builtin_amdgcn_exp2f(v0.y + v1.y);
            s.z = __builtin_amdgcn_exp2f(v0.z + v1.z);
            s.w = __builtin_amdgcn_exp2f(v0.w + v1.w);
            *(float4*)&st[row >> 5][row & 31][c4] = s;
        }
        __syncthreads();

        const int hw = 32 * w;                 // wave's h window
#pragma unroll
        for (int hh = 0; hh < 32; hh += 4) {
            const float4 w4 = *(const float4*)&wv[hw + hh];   // wave-uniform
            const float* wa = (const float*)&w4;
            float4 q4[4], k4[4];
#pragma unroll
            for (int i = 0; i < 4; ++i) q4[i] = *(float4*)&st[0][ql + 8 * i][hw + hh];
#pragma unroll
            for (int j = 0; j < 4; ++j) k4[j] = *(float4*)&st[1][kl + 8 * j][hw + hh];
#pragma unroll
            for (int i = 0; i < 4; ++i) {
                const float* qa = (const float*)&q4[i];
#pragma unroll
                for (int j = 0; j < 4; ++j) {
                    const float* ka = (const float*)&k4[j];
#pragma unroll
                    for (int c = 0; c < 4; ++c) {
                        float d = __builtin_fmaf(qa[c], ka[c], 1.0f);
                        acc[i][j] += wa[c] * __builtin_amdgcn_rcpf(d);
                    }
                }
            }
        }
        __syncthreads();   // staging dead; red may now overwrite it

        // wave-partial accs -> red
#pragma unroll
        for (int i = 0; i < 4; ++i)
#pragma unroll
            for (int j = 0; j < 4; ++j)
                red[w * 1056 + (ql + 8 * i) * 33 + (kl + 8 * j)] = acc[i][j];
    }
    __syncthreads();

    // ---- combine across waves, masked exp2, pT + psum ----
    float pvv[2];
#pragma unroll
    for (int u = 0; u < 2; ++u) {
        int n = t + 512 * u;               // 0..1023
        int q = n >> 5, k = n & 31;
        float s = 0.f;
        if (vl > 0) {
#pragma unroll
            for (int ww = 0; ww < 8; ++ww) s += red[ww * 1056 + q * 33 + k];
        }
        int kg = k0 + k;
        float pv;
        if (vl == 0) pv = 1.0f;            // uniform row (ref behavior)
        else pv = (kg < vl) ? __builtin_amdgcn_exp2f(NEG_TWO_LOG2E * s) : 0.0f;
        pT[k][q] = pv;
        pvv[u] = pv;
    }
    // psum: lanes 0-31 / 32-63 of each wave share a q; reduce within halves
    float s0 = pvv[0], s1 = pvv[1];
#pragma unroll
    for (int off = 1; off < 32; off <<= 1) {
        s0 += __shfl_xor(s0, off);
        s1 += __shfl_xor(s1, off);
    }
    if ((l & 31) == 0) {
        int qa = 2 * w + (l >> 5);         // q for u=0; u=1 is qa+16
        psum[((size_t)ksb * BB + b) * QQ + q0 + qa]      = s0;
        psum[((size_t)ksb * BB + b) * QQ + q0 + qa + 16] = s1;
    }
    __syncthreads();

    // ---- av phase: thread = (4d x 4q), 8 q-groups over 8 waves ----
    const float* VB = V + ((size_t)b * KK + k0) * DD;
    const int d4 = (t & 63) << 2;
    const int qg = w << 2;                 // 0,4,...,28
    float4 a4[4] = {};
#pragma unroll 4
    for (int k = 0; k < KCH; ++k) {
        float4 v4 = *(const float4*)&VB[(size_t)k * DD + d4];   // coalesced
        float4 p4 = *(float4*)&pT[k][qg];                       // broadcast
        a4[0].x += p4.x * v4.x; a4[0].y += p4.x * v4.y; a4[0].z += p4.x * v4.z; a4[0].w += p4.x * v4.w;
        a4[1].x += p4.y * v4.x; a4[1].y += p4.y * v4.y; a4[1].z += p4.y * v4.z; a4[1].w += p4.y * v4.w;
        a4[2].x += p4.z * v4.x; a4[2].y += p4.z * v4.y; a4[2].z += p4.z * v4.z; a4[2].w += p4.z * v4.w;
        a4[3].x += p4.w * v4.x; a4[3].y += p4.w * v4.y; a4[3].z += p4.w * v4.z; a4[3].w += p4.w * v4.w;
    }
#pragma unroll
    for (int qi = 0; qi < 4; ++qi) {
        int q = q0 + qg + qi;
        *(float4*)&partial[(((size_t)ksb * BB + b) * QQ + q) * DD + d4] = a4[qi];
    }
}

// ---------------------------------------------------------------------------
// K3: mask-aware reduce over the nch(b) live chunks + softmax normalization.
// ---------------------------------------------------------------------------
__global__ __launch_bounds__(256) void av_reduce(const float* __restrict__ partial,
                                                 const float* __restrict__ psum,
                                                 const int* __restrict__ vlen,
                                                 float* __restrict__ out) {
    const int i  = blockIdx.x * 256 + threadIdx.x;   // float4 index, 65536 total
    const int bq = i >> 6;                           // b*QQ + q
    const int b  = bq >> 7;
    const int vl = vlen[b];
    const int nch = (vl == 0) ? KSP : ((vl + KCH - 1) / KCH);

    float S = 0.f;
    for (int ks = 0; ks < nch; ++ks) S += psum[(size_t)ks * (BB * QQ) + bq];

    const float4* p4 = (const float4*)partial;
    const int stride4 = BB * QQ * DD / 4;            // 65536
    float4 s = {0.f, 0.f, 0.f, 0.f};
    for (int ks = 0; ks < nch; ++ks) {
        float4 x = p4[(size_t)ks * stride4 + i];
        s.x += x.x; s.y += x.y; s.z += x.z; s.w += x.w;
    }
    const float inv = 1.0f / S;   // S>0 always: p>=8e-12 unmasked, vl==0 -> p=1
    s.x *= inv; s.y *= inv; s.z *= inv; s.w *= inv;
    ((float4*)out)[i] = s;
}

// ---------------------------------------------------------------------------
extern "C" void kernel_launch(void* const* d_in, const int* in_sizes, int n_in,
                              void* d_out, int out_size, void* d_ws, size_t ws_size,
                              hipStream_t stream) {
    const float* queries = (const float*)d_in[0];   // [B,Q,D]
    const float* keys    = (const float*)d_in[1];   // [B,K,D]
    const float* values  = (const float*)d_in[2];   // [B,K,D]
    const float* W_q     = (const float*)d_in[3];   // [H,D]
    const float* W_k     = (const float*)d_in[4];   // [H,D]
    const float* w_v     = (const float*)d_in[5];   // [H]
    const int*   vlen    = (const int*)d_in[6];     // [B]
    float* out = (float*)d_out;

    float* ws      = (float*)d_ws;
    float* pp      = ws;                                  // 2*PSTRIDE = 18.9 MB
    float* psum    = pp + 2 * PSTRIDE;                    // KSP*B*Q = 32768
    float* partial = psum + (size_t)KSP * BB * QQ;        // 33.5 MB
    // no aliasing: scoreav reads pp while writing partial. ~53 MB of ws.

    // D-split Q+K projection (pp halves, no exp2), mask-skipped
    proj_kernel<<<dim3(RTOT / 64, HH / 64, 2), 256, 0, stream>>>(
        queries, keys, W_q, W_k, vlen, pp);

    // Fused score + A*V, h-sliced 8-wave blocks, D-half combine in staging
    scoreav_kernel<<<dim3(KSP * 4 * BB, 1, 1), 512, 0, stream>>>(
        pp, w_v, vlen, values, partial, psum);

    // Mask-aware reduce + softmax normalization
    av_reduce<<<dim3(BB * QQ * DD / 4 / 256, 1, 1), 256, 0, stream>>>(
        partial, psum, vlen, out);
}